// Round 7
// baseline (3325.556 us; speedup 1.0000x reference)
//
#include <hip/hip_runtime.h>
#include <stdint.h>

typedef float f32x4 __attribute__((ext_vector_type(4)));
typedef long long2_t __attribute__((ext_vector_type(2)));
typedef unsigned int uint;

#define NB 2048
#define NS 128
#define NI 8
#define NH 256
#define NG 1024   // 4*H
#define NK 50

#define A_SC 16.0f
#define W_SC 32.0f
#define INV_SC (1.0f/(A_SC*W_SC))

// IDM constants
#define DT_    0.1f
#define V_DES_ 12.64798288f
#define T_HW_  0.50284384f
#define A_MAX_ 0.10033688f
#define B_SAFE_ 4.98937183f
#define S0_    0.13082412f

// LDS h buffer [16 rows][256 B] with 16B-granule XOR swizzle (r6-proven):
// unit u -> boff(u) = ((u>>3)&3)*64 + ((u>>6)&3)*16 + ((u>>5)&1)*8 + (u&7)
// A-frag read for (kgrp,kbh): 16B at (lrow<<8) + ((((kgrp<<2)+kbh)^lrow)&15)<<4
#define HADDR16(row, boff) (((row) << 8) + (((((boff) >> 4) ^ (row)) & 15) << 4) + ((boff) & 15))

#define CL(x) __builtin_amdgcn_fmed3f((x), -15.0f, 15.0f)

__device__ __forceinline__ uint8_t f2fp8(float v) {
    int r = __builtin_amdgcn_cvt_pk_fp8_f32(v, v, 0, false);
    return (uint8_t)(r & 0xff);
}

// ---------------- pre-pass kernels ----------------
__global__ void k_pack(const float* __restrict__ W, uint8_t* __restrict__ out,
                       int tiles, int KB, int Nsrc, int Ksrc) {
    int gid = blockIdx.x * 256 + threadIdx.x;
    int total = tiles * KB * 64;
    if (gid >= total) return;
    int lane = gid & 63;
    int kb   = (gid >> 6) % KB;
    int tile = gid / (64 * KB);
    int n = tile * 16 + (lane & 15);
    int kbase = kb * 32 + (lane >> 4) * 8;
    uint64_t wbits = 0;
    #pragma unroll
    for (int j = 0; j < 8; ++j) {
        int k = kbase + j;
        float v = (n < Nsrc && k < Ksrc) ? W[(size_t)n * Ksrc + k] * W_SC : 0.0f;
        wbits |= ((uint64_t)f2fp8(v)) << (8 * j);
    }
    *(uint64_t*)(out + (size_t)gid * 8) = wbits;
}

__global__ void k_bias(const float* __restrict__ bih0, const float* __restrict__ bhh0,
                       const float* __restrict__ bih1, const float* __restrict__ bhh1,
                       float* __restrict__ b0, float* __restrict__ b1) {
    int i = blockIdx.x * 256 + threadIdx.x;
    if (i < NG) b0[i] = bih0[i] + bhh0[i];
    else if (i < 2 * NG) b1[i - NG] = bih1[i - NG] + bhh1[i - NG];
}

__global__ void k_x8(const float* __restrict__ x, uint8_t* __restrict__ x8) {
    int i = blockIdx.x * 256 + threadIdx.x;
    if (i < NB * NS * NI) x8[i] = f2fp8(x[i] * A_SC);
}

// fused in-register LSTM cell update: 4 rows of one unit; 7 trans/update
__device__ __forceinline__ void cell_update(const f32x4 acc[4], const float bs[4],
                                            float cv[4], uint8_t* __restrict__ dst,
                                            const int wa[4]) {
    #pragma unroll
    for (int r = 0; r < 4; ++r) {
        float iv = CL(fmaf(acc[0][r], INV_SC, bs[0]));
        float fv = CL(fmaf(acc[1][r], INV_SC, bs[1]));
        float gv = CL(fmaf(acc[2][r], INV_SC, bs[2]));
        float ov = CL(fmaf(acc[3][r], INV_SC, bs[3]));
        float ei = __expf(-iv), ef = __expf(-fv);
        float eg = __expf(2.0f * gv), eo = __expf(-ov);
        // c' = [c*(1+ei)*(eg+1) + (1+ef)*(eg-1)] / [(1+ei)*(eg+1)*(1+ef)]
        float t1 = (1.0f + ei) * (eg + 1.0f);
        float t2 = 1.0f + ef;
        float num = fmaf(cv[r] * t1, 1.0f, t2 * (eg - 1.0f));
        float cn = (cv[r] * t1 + t2 * (eg - 1.0f)) * __builtin_amdgcn_rcpf(t1 * t2);
        (void)num;
        cv[r] = cn;
        float cc = CL(cn);
        float ec = __expf(2.0f * cc);
        // h = sigm(o)*tanh(c') = (ec-1)/((1+eo)*(ec+1))
        float hh = (ec - 1.0f) * __builtin_amdgcn_rcpf((1.0f + eo) * (ec + 1.0f));
        dst[wa[r]] = f2fp8(hh * A_SC);
    }
}

// ---------------- exchange-free weight-stationary LSTM ----------------
// 128 WGs x 1024 threads; WG owns 16 batch rows and ALL 256 hidden units of
// both layers. Weights (100 fp8 B-frags/wave) pinned in AGPRs for the whole
// kernel. h state lives in LDS only; 2 __syncthreads per timestep; ZERO
// inter-WG communication, no atomics, no cooperative launch.
__global__ __launch_bounds__(1024, 4)
void k_lstm7(const uint8_t* __restrict__ x8,
             const uint8_t* __restrict__ Wih0P, const uint8_t* __restrict__ Whh0P,
             const uint8_t* __restrict__ Wih1P, const uint8_t* __restrict__ Whh1P,
             const uint8_t* __restrict__ WfcP,
             const float* __restrict__ bias0, const float* __restrict__ bias1,
             const float* __restrict__ bfc,
             float* __restrict__ out) {
    __shared__ uint8_t h0st[2][4096];   // [parity][HADDR16(16 rows, 256 B)]
    __shared__ uint8_t h1st[2][4096];

    const int tid  = threadIdx.x;
    const int lane = tid & 63, w = tid >> 6;       // wave w = unit-tile (0..15)
    const int lrow = lane & 15, kgrp = lane >> 4;
    const int rowbase = blockIdx.x * 16;

    // ---- all weights, pinned: 100 frags = 200 AGPRs per lane ----
    long wI0[4], wH0[4][8], wI1[4][8], wH1[4][8];
    #pragma unroll
    for (int g = 0; g < 4; ++g) {
        const int T = g * 16 + w;
        wI0[g] = *(const long*)(Wih0P + ((size_t)T * 64 + lane) * 8);
        #pragma unroll
        for (int kb = 0; kb < 8; ++kb) {
            wH0[g][kb] = *(const long*)(Whh0P + (((size_t)T * 8 + kb) * 64 + lane) * 8);
            wI1[g][kb] = *(const long*)(Wih1P + (((size_t)T * 8 + kb) * 64 + lane) * 8);
            wH1[g][kb] = *(const long*)(Whh1P + (((size_t)T * 8 + kb) * 64 + lane) * 8);
        }
    }
    #pragma unroll
    for (int g = 0; g < 4; ++g) {
        asm volatile("" : "+a"(wI0[g]));
        #pragma unroll
        for (int kb = 0; kb < 8; ++kb)
            asm volatile("" : "+a"(wH0[g][kb]), "+a"(wI1[g][kb]), "+a"(wH1[g][kb]));
    }

    // nonlin ownership: this lane owns unit u (C-layout col), rows kgrp*4+r
    const int u = w * 16 + lrow;
    float bs0[4], bs1[4];
    #pragma unroll
    for (int g = 0; g < 4; ++g) { bs0[g] = bias0[g * 256 + u]; bs1[g] = bias1[g * 256 + u]; }
    const int boffu = ((u >> 3) & 3) * 64 + ((u >> 6) & 3) * 16 + ((u >> 5) & 1) * 8 + (u & 7);
    int wa[4];
    #pragma unroll
    for (int r = 0; r < 4; ++r) wa[r] = HADDR16(kgrp * 4 + r, boffu);

    float c0v[4] = {0,0,0,0}, c1v[4] = {0,0,0,0};

    {   // zero h state (h[-1] = 0)
        int4 z = {0,0,0,0};
        if (tid < 512) ((int4*)h0st)[tid]; // (no-op read avoided below)
        if (tid < 512) ((int4*)h0st)[tid] = z; else ((int4*)h1st)[tid - 512] = z;
    }
    __syncthreads();

    long xreg = 0;
    if (kgrp == 0) xreg = *(const long*)(x8 + (size_t)(rowbase + lrow) * (NS * NI));

    for (int p = 0; p < NS; ++p) {
        const int pa = p & 1, pb = pa ^ 1;

        // ===== layer 0: x_t@Wih0^T + h0(p-1)@Whh0^T (in-register C) =====
        f32x4 acc[4];
        #pragma unroll
        for (int g = 0; g < 4; ++g)
            acc[g] = __builtin_amdgcn_mfma_f32_16x16x32_fp8_fp8(xreg, wI0[g], (f32x4){0,0,0,0}, 0, 0, 0);
        #pragma unroll
        for (int kbh = 0; kbh < 4; ++kbh) {
            const int gsw = ((((kgrp << 2) + kbh) ^ lrow) & 15) << 4;
            long2_t q = *(const long2_t*)&h0st[pa][(lrow << 8) + gsw];
            #pragma unroll
            for (int g = 0; g < 4; ++g) {
                acc[g] = __builtin_amdgcn_mfma_f32_16x16x32_fp8_fp8(q.x, wH0[g][2*kbh],   acc[g], 0, 0, 0);
                acc[g] = __builtin_amdgcn_mfma_f32_16x16x32_fp8_fp8(q.y, wH0[g][2*kbh+1], acc[g], 0, 0, 0);
            }
        }
        // prefetch next x while MFMA results settle
        if (kgrp == 0 && p + 1 < NS)
            xreg = *(const long*)(x8 + (size_t)(rowbase + lrow) * (NS * NI) + (p + 1) * 8);

        // nonlin0 (in-register) -> h0(p) into parity pb
        cell_update(acc, bs0, c0v, h0st[pb], wa);
        __syncthreads();   // B1: h0(p) visible to all waves

        // ===== layer 1: h0(p)@Wih1^T + h1(p-1)@Whh1^T =====
        f32x4 acc1[4];
        #pragma unroll
        for (int g = 0; g < 4; ++g) acc1[g] = (f32x4){0,0,0,0};
        #pragma unroll
        for (int kbh = 0; kbh < 4; ++kbh) {
            const int gsw = ((((kgrp << 2) + kbh) ^ lrow) & 15) << 4;
            long2_t q = *(const long2_t*)&h0st[pb][(lrow << 8) + gsw];
            long2_t s = *(const long2_t*)&h1st[pa][(lrow << 8) + gsw];
            #pragma unroll
            for (int g = 0; g < 4; ++g) {
                acc1[g] = __builtin_amdgcn_mfma_f32_16x16x32_fp8_fp8(q.x, wI1[g][2*kbh],   acc1[g], 0, 0, 0);
                acc1[g] = __builtin_amdgcn_mfma_f32_16x16x32_fp8_fp8(q.y, wI1[g][2*kbh+1], acc1[g], 0, 0, 0);
                acc1[g] = __builtin_amdgcn_mfma_f32_16x16x32_fp8_fp8(s.x, wH1[g][2*kbh],   acc1[g], 0, 0, 0);
                acc1[g] = __builtin_amdgcn_mfma_f32_16x16x32_fp8_fp8(s.y, wH1[g][2*kbh+1], acc1[g], 0, 0, 0);
            }
        }
        // nonlin1 -> h1(p) into parity pb
        cell_update(acc1, bs1, c1v, h1st[pb], wa);
        __syncthreads();   // B2: h1(p) visible; next phase reads pb as pa
    }

    // ===== FC head: y = h1(127) @ Wfc^T + bfc ; h1(127) is in h1st[0] =====
    if (w < 4) {
        f32x4 a = {0,0,0,0};
        #pragma unroll
        for (int kbh = 0; kbh < 4; ++kbh) {
            const int gsw = ((((kgrp << 2) + kbh) ^ lrow) & 15) << 4;
            long2_t q = *(const long2_t*)&h1st[0][(lrow << 8) + gsw];
            long b0_ = *(const long*)(WfcP + (((size_t)w * 8 + 2 * kbh) * 64 + lane) * 8);
            long b1_ = *(const long*)(WfcP + (((size_t)w * 8 + 2 * kbh + 1) * 64 + lane) * 8);
            a = __builtin_amdgcn_mfma_f32_16x16x32_fp8_fp8(q.x, b0_, a, 0, 0, 0);
            a = __builtin_amdgcn_mfma_f32_16x16x32_fp8_fp8(q.y, b1_, a, 0, 0, 0);
        }
        const int col = w * 16 + lrow;
        if (col < NK) {
            float bb = bfc[col];
            #pragma unroll
            for (int r = 0; r < 4; ++r)
                out[(size_t)(rowbase + kgrp * 4 + r) * NK + col] = a[r] * INV_SC + bb;
        }
    }
}

// ---------------- IDM rollout (exact fp32) ----------------
__global__ void k_idm(const float* __restrict__ x, const float* __restrict__ s0,
                      const float* __restrict__ vl, float* __restrict__ out) {
    int b = blockIdx.x * 256 + threadIdx.x;
    if (b >= NB) return;
    float v = x[(size_t)b * NS * NI + (NS - 1) * NI + 0];
    float s = s0[b];
    float vlead = vl[b];
    const float den = 2.0f * sqrtf(A_MAX_ * B_SAFE_) + 1e-6f;
    float* o = out + (size_t)NB * NK + (size_t)b * NK;
    #pragma unroll 1
    for (int k = 0; k < NK; ++k) {
        float dv = vlead - v;
        float sc = fmaxf(s, 1e-6f);
        float ss = fmaxf(S0_ + v * T_HW_ + v * dv / den, 0.0f);
        float a = A_MAX_ * (1.0f - v / V_DES_ - (ss / sc) * (ss / sc));
        v = fmaxf(v + DT_ * a, 0.0f);
        s = fmaxf(s + dv * DT_, 1e-6f);
        o[k] = v;
    }
}

// ---------------- launch ----------------
extern "C" void kernel_launch(void* const* d_in, const int* in_sizes, int n_in,
                              void* d_out, int out_size, void* d_ws, size_t ws_size,
                              hipStream_t stream) {
    const float* x    = (const float*)d_in[0];
    const float* s0   = (const float*)d_in[1];
    const float* vl   = (const float*)d_in[2];
    const float* Wih0 = (const float*)d_in[3];
    const float* Whh0 = (const float*)d_in[4];
    const float* bih0 = (const float*)d_in[5];
    const float* bhh0 = (const float*)d_in[6];
    const float* Wih1 = (const float*)d_in[7];
    const float* Whh1 = (const float*)d_in[8];
    const float* bih1 = (const float*)d_in[9];
    const float* bhh1 = (const float*)d_in[10];
    const float* Wfc  = (const float*)d_in[11];
    const float* bfc  = (const float*)d_in[12];
    float* out = (float*)d_out;

    uint8_t* ws = (uint8_t*)d_ws;
    size_t off = 0;
    auto alloc = [&](size_t n) { uint8_t* p = ws + off; off += (n + 255) & ~(size_t)255; return p; };
    uint8_t* Wih0P = alloc(64 * 1 * 64 * 8);
    uint8_t* Whh0P = alloc(64 * 8 * 64 * 8);
    uint8_t* Wih1P = alloc(64 * 8 * 64 * 8);
    uint8_t* Whh1P = alloc(64 * 8 * 64 * 8);
    uint8_t* WfcP  = alloc(4 * 8 * 64 * 8);
    float* b0 = (float*)alloc(NG * 4);
    float* b1 = (float*)alloc(NG * 4);
    uint8_t* x8 = alloc((size_t)NB * NS * NI);

    k_pack<<<(64 * 1 * 64 + 255) / 256, 256, 0, stream>>>(Wih0, Wih0P, 64, 1, NG, NI);
    k_pack<<<(64 * 8 * 64 + 255) / 256, 256, 0, stream>>>(Whh0, Whh0P, 64, 8, NG, NH);
    k_pack<<<(64 * 8 * 64 + 255) / 256, 256, 0, stream>>>(Wih1, Wih1P, 64, 8, NG, NH);
    k_pack<<<(64 * 8 * 64 + 255) / 256, 256, 0, stream>>>(Whh1, Whh1P, 64, 8, NG, NH);
    k_pack<<<(4 * 8 * 64 + 255) / 256, 256, 0, stream>>>(Wfc, WfcP, 4, 8, NK, NH);
    k_bias<<<(2 * NG + 255) / 256, 256, 0, stream>>>(bih0, bhh0, bih1, bhh1, b0, b1);
    k_x8<<<(NB * NS * NI + 255) / 256, 256, 0, stream>>>(x, x8);

    k_lstm7<<<128, 1024, 0, stream>>>(x8, Wih0P, Whh0P, Wih1P, Whh1P, WfcP, b0, b1, bfc, out);
    k_idm<<<(NB + 255) / 256, 256, 0, stream>>>(x, s0, vl, out);
}

// Round 8
// 973.142 us; speedup vs baseline: 3.4173x; 3.4173x over previous
//
#include <hip/hip_runtime.h>
#include <stdint.h>

typedef float f32x4 __attribute__((ext_vector_type(4)));
typedef long long2_t __attribute__((ext_vector_type(2)));
typedef unsigned int uint;
typedef unsigned long long ull;

#define NB 2048
#define NS 128
#define NI 8
#define NH 256
#define NG 1024   // 4*H
#define NK 50

#define A_SC 16.0f
#define W_SC 32.0f
#define SC_PROD 512.0f
#define INV_SC (1.0f/512.0f)

// IDM constants
#define DT_    0.1f
#define V_DES_ 12.64798288f
#define T_HW_  0.50284384f
#define A_MAX_ 0.10033688f
#define B_SAFE_ 4.98937183f
#define S0_    0.13082412f

// LDS h-stage [32 rows][256 B]; 16B-granule XOR swizzle
#define HADDR16(row, boff) (((row) << 8) + (((((boff) >> 4) ^ ((row) & 15)) & 15) << 4) + ((boff) & 15))
// gate buffer: [32 rows][256 cols] f32, XOR column swizzle (16-col granular, float4-safe)
#define GIDX(row, col) (((row) << 8) + ((col) ^ (((row) & 12) << 2)))

__device__ __forceinline__ uint8_t f2fp8(float v) {
    int r = __builtin_amdgcn_cvt_pk_fp8_f32(v, v, 0, false);
    return (uint8_t)(r & 0xff);
}
__device__ __forceinline__ float sigm(float x) { return 1.0f / (1.0f + __expf(-x)); }
__device__ __forceinline__ float tanh_f(float x) {
    x = fminf(fmaxf(x, -15.0f), 15.0f);
    float e = __expf(2.0f * x);
    return (e - 1.0f) / (e + 1.0f);
}

// ---------------- pre-pass kernels ----------------
__global__ void k_pack(const float* __restrict__ W, uint8_t* __restrict__ out,
                       int tiles, int KB, int Nsrc, int Ksrc) {
    int gid = blockIdx.x * 256 + threadIdx.x;
    int total = tiles * KB * 64;
    if (gid >= total) return;
    int lane = gid & 63;
    int kb   = (gid >> 6) % KB;
    int tile = gid / (64 * KB);
    int n = tile * 16 + (lane & 15);
    int kbase = kb * 32 + (lane >> 4) * 8;
    uint64_t wbits = 0;
    #pragma unroll
    for (int j = 0; j < 8; ++j) {
        int k = kbase + j;
        float v = (n < Nsrc && k < Ksrc) ? W[(size_t)n * Ksrc + k] * W_SC : 0.0f;
        wbits |= ((uint64_t)f2fp8(v)) << (8 * j);
    }
    *(uint64_t*)(out + (size_t)gid * 8) = wbits;
}

__global__ void k_bias(const float* __restrict__ bih0, const float* __restrict__ bhh0,
                       const float* __restrict__ bih1, const float* __restrict__ bhh1,
                       float* __restrict__ b0, float* __restrict__ b1) {
    int i = blockIdx.x * 256 + threadIdx.x;
    if (i < NG) b0[i] = (bih0[i] + bhh0[i]) * SC_PROD;
    else if (i < 2 * NG) b1[i - NG] = (bih1[i - NG] + bhh1[i - NG]) * SC_PROD;
}

__global__ void k_x8(const float* __restrict__ x, uint8_t* __restrict__ x8) {
    int i = blockIdx.x * 256 + threadIdx.x;
    if (i < NB * NS * NI) x8[i] = f2fp8(x[i] * A_SC);
}

// ---------------- same-XCD-cluster pipelined weight-stationary LSTM ----------------
// 256 WGs = 64 batch-groups (32 rows) x 4 gate-slices (64 units), 1 WG/CU.
// CLUSTER MAPPING: group g = blk&63 -> its 4 slices sit on blocks
// {g, g+64, g+128, g+192}, all == g (mod 8) -> SAME XCD -> publish/restage/
// counter traffic stays in the shared per-XCD L2 (~200cy instead of ~900cy
// cross-XCD fabric rtt). Weights: 50 fp8 B-frags/wave pinned in AGPRs.
__global__ __launch_bounds__(512, 2)
void k_lstm8(const uint8_t* __restrict__ x8,
             const uint8_t* __restrict__ Wih0P, const uint8_t* __restrict__ Whh0P,
             const uint8_t* __restrict__ Wih1P, const uint8_t* __restrict__ Whh1P,
             const uint8_t* __restrict__ WfcP,
             const float* __restrict__ bias0, const float* __restrict__ bias1,
             const float* __restrict__ bfc,
             uint8_t* __restrict__ h0g, uint8_t* __restrict__ h1g,
             uint* __restrict__ ctrs, float* __restrict__ out) {
    __shared__ uint8_t h0st[8192];   // h0[p-1], fp8, HADDR16 layout
    __shared__ uint8_t h1st[8192];   // h1[p-2]
    __shared__ float gA[8192];       // layer0 gates (32 x 256), GIDX, x512 domain
    __shared__ float gB[8192];       // layer1 gates

    const int tid  = threadIdx.x;
    const int lane = tid & 63, w = tid >> 6;
    const int lrow = lane & 15, kgrp = lane >> 4;
    const int grp  = blockIdx.x & 63, slc = blockIdx.x >> 6;   // same-XCD cluster
    const int rowbase = grp * 32;
    const int g = w & 3, ubk = w >> 2;           // wave: gate g, unit-block half

    // ---- persistent weight fragments: 50 frags pinned in AGPRs ----
    long wI0[2], wH0[2][8], wI1[2][8], wH1[2][8];
    #pragma unroll
    for (int cc = 0; cc < 2; ++cc) {
        int T = g * 16 + slc * 4 + ubk * 2 + cc;
        wI0[cc] = *(const long*)(Wih0P + ((size_t)T * 64 + lane) * 8);
        #pragma unroll
        for (int kb = 0; kb < 8; ++kb) {
            wH0[cc][kb] = *(const long*)(Whh0P + (((size_t)T * 8 + kb) * 64 + lane) * 8);
            wI1[cc][kb] = *(const long*)(Wih1P + (((size_t)T * 8 + kb) * 64 + lane) * 8);
            wH1[cc][kb] = *(const long*)(Whh1P + (((size_t)T * 8 + kb) * 64 + lane) * 8);
        }
    }
    #pragma unroll
    for (int cc = 0; cc < 2; ++cc) {
        asm volatile("" : "+a"(wI0[cc]));
        #pragma unroll
        for (int kb = 0; kb < 8; ++kb)
            asm volatile("" : "+a"(wH0[cc][kb]), "+a"(wI1[cc][kb]), "+a"(wH1[cc][kb]));
    }

    // staging bias (x512 domain), one per cc (col fixed per lane)
    float bw0[2], bw1[2];
    #pragma unroll
    for (int cc = 0; cc < 2; ++cc) {
        int n = g * 256 + slc * 64 + ubk * 32 + cc * 16 + lrow;
        bw0[cc] = bias0[n]; bw1[cc] = bias1[n];
    }

    // nonlinearity mapping: thread -> (row nrow, 4 adjacent units ub4..ub4+3)
    const int nrow = tid >> 4;
    const int ub4  = (tid & 15) * 4;
    float c0v[4] = {0,0,0,0}, c1v[4] = {0,0,0,0};

    { int4 z = {0,0,0,0}; ((int4*)h0st)[tid] = z; ((int4*)h1st)[tid] = z; }
    __syncthreads();

    uint8_t* const h0gg = h0g + (size_t)grp * 16384;   // [parity][32][256]
    uint8_t* const h1gg = h1g + (size_t)grp * 16384;
    uint* const ctr0 = ctrs + grp * 32;
    uint* const ctr1 = ctrs + grp * 32 + 16;
    uint t0 = 0, t1 = 0;

    const int rrow = tid & 31, seg = tid >> 5;         // restage mapping: 16B/thread
    const int rkb = seg >> 1, rkg = (seg & 1) << 1;
    const int rboff0 = rkg * 64 + rkb * 8, rboff1 = (rkg + 1) * 64 + rkb * 8;

#define WAITC(CP, TGT) do { \
    if (tid == 0) { \
        uint gd_ = 0; \
        while (__hip_atomic_load((CP), __ATOMIC_RELAXED, __HIP_MEMORY_SCOPE_AGENT) < (TGT)) { \
            __builtin_amdgcn_s_sleep(1); \
            if (++gd_ > (1u << 24)) break; \
        } \
    } \
    __syncthreads(); \
} while (0)

    for (int p = 0; p <= NS; ++p) {
        // ===== C': wait + issue h1(p-2) restage loads (rtt hides under layer0) =====
        ull pr0 = 0, pr1 = 0;
        if (p >= 2) {
            WAITC(ctr1, t1);
            const uint8_t* s = h1gg + (size_t)(p & 1) * 8192 + rrow * 256 + seg * 16;
            pr0 = __hip_atomic_load((const ull*)s,       __ATOMIC_RELAXED, __HIP_MEMORY_SCOPE_AGENT);
            pr1 = __hip_atomic_load((const ull*)(s + 8), __ATOMIC_RELAXED, __HIP_MEMORY_SCOPE_AGENT);
        }

        // ===== A: layer0 MFMA (t=p): x_t@Wih0^T + h0(p-1)@Whh0^T -> gA =====
        if (p < NS) {
            f32x4 acc[2][2];
            #pragma unroll
            for (int rr = 0; rr < 2; ++rr) { acc[rr][0] = (f32x4){0,0,0,0}; acc[rr][1] = (f32x4){0,0,0,0}; }
            #pragma unroll
            for (int rr = 0; rr < 2; ++rr) {
                long ax = 0;
                if (kgrp == 0) ax = *(const long*)(x8 + (size_t)(rowbase + rr * 16 + lrow) * (NS * NI) + p * 8);
                acc[rr][0] = __builtin_amdgcn_mfma_f32_16x16x32_fp8_fp8(ax, wI0[0], acc[rr][0], 0, 0, 0);
                acc[rr][1] = __builtin_amdgcn_mfma_f32_16x16x32_fp8_fp8(ax, wI0[1], acc[rr][1], 0, 0, 0);
                #pragma unroll
                for (int kbh = 0; kbh < 4; ++kbh) {
                    const int gsw = ((((kgrp << 2) + kbh) ^ lrow) & 15) << 4;
                    long2_t q = *(const long2_t*)&h0st[((rr * 16 + lrow) << 8) + gsw];
                    acc[rr][0] = __builtin_amdgcn_mfma_f32_16x16x32_fp8_fp8(q.x, wH0[0][2*kbh],   acc[rr][0], 0, 0, 0);
                    acc[rr][0] = __builtin_amdgcn_mfma_f32_16x16x32_fp8_fp8(q.y, wH0[0][2*kbh+1], acc[rr][0], 0, 0, 0);
                    acc[rr][1] = __builtin_amdgcn_mfma_f32_16x16x32_fp8_fp8(q.x, wH0[1][2*kbh],   acc[rr][1], 0, 0, 0);
                    acc[rr][1] = __builtin_amdgcn_mfma_f32_16x16x32_fp8_fp8(q.y, wH0[1][2*kbh+1], acc[rr][1], 0, 0, 0);
                }
            }
            #pragma unroll
            for (int rr = 0; rr < 2; ++rr)
            #pragma unroll
            for (int cc = 0; cc < 2; ++cc) {
                const int colw = g * 64 + ubk * 32 + cc * 16 + lrow;
                #pragma unroll
                for (int r = 0; r < 4; ++r)
                    gA[GIDX(rr * 16 + kgrp * 4 + r, colw)] = acc[rr][cc][r] + bw0[cc];
            }
        }
        __syncthreads();   // S1: gates0 staged

        // ===== B: nonlin0 + publish h0(p); h1st LDS-write from prefetch =====
        if (p < NS) {
            float4 q0 = *(float4*)&gA[GIDX(nrow, ub4)];
            float4 q1 = *(float4*)&gA[GIDX(nrow, 64 + ub4)];
            float4 q2 = *(float4*)&gA[GIDX(nrow, 128 + ub4)];
            float4 q3 = *(float4*)&gA[GIDX(nrow, 192 + ub4)];
            float hh[4];
            #pragma unroll
            for (int u = 0; u < 4; ++u) {
                float iv = (&q0.x)[u] * INV_SC, fv = (&q1.x)[u] * INV_SC;
                float gv = (&q2.x)[u] * INV_SC, ov = (&q3.x)[u] * INV_SC;
                float c = sigm(fv) * c0v[u] + sigm(iv) * tanh_f(gv);
                c0v[u] = c;
                hh[u] = sigm(ov) * tanh_f(c) * A_SC;
            }
            int pk = __builtin_amdgcn_cvt_pk_fp8_f32(hh[0], hh[1], 0, false);
            pk = __builtin_amdgcn_cvt_pk_fp8_f32(hh[2], hh[3], pk, true);
            __hip_atomic_store((uint*)(h0gg + (size_t)(p & 1) * 8192 + nrow * 256 + slc * 64 + ub4),
                               (uint)pk, __ATOMIC_RELAXED, __HIP_MEMORY_SCOPE_AGENT);
        }
        if (p >= 2) {
            *(ull*)&h1st[HADDR16(rrow, rboff0)] = pr0;
            *(ull*)&h1st[HADDR16(rrow, rboff1)] = pr1;
        }
        __syncthreads();   // S2: h0 publish drained; h1st ready
        if (p < NS) { if (tid == 0) __hip_atomic_fetch_add(ctr0, 1u, __ATOMIC_RELAXED, __HIP_MEMORY_SCOPE_AGENT); t0 += 4; }

        // ===== D: layer1 MFMA (t=p-1): h0(p-1)@Wih1^T + h1(p-2)@Whh1^T -> gB =====
        if (p >= 1) {
            f32x4 acc[2][2];
            #pragma unroll
            for (int rr = 0; rr < 2; ++rr) { acc[rr][0] = (f32x4){0,0,0,0}; acc[rr][1] = (f32x4){0,0,0,0}; }
            #pragma unroll
            for (int rr = 0; rr < 2; ++rr) {
                #pragma unroll
                for (int kbh = 0; kbh < 4; ++kbh) {
                    const int gsw = ((((kgrp << 2) + kbh) ^ lrow) & 15) << 4;
                    long2_t q = *(const long2_t*)&h0st[((rr * 16 + lrow) << 8) + gsw];
                    long2_t r2 = *(const long2_t*)&h1st[((rr * 16 + lrow) << 8) + gsw];
                    acc[rr][0] = __builtin_amdgcn_mfma_f32_16x16x32_fp8_fp8(q.x,  wI1[0][2*kbh],   acc[rr][0], 0, 0, 0);
                    acc[rr][0] = __builtin_amdgcn_mfma_f32_16x16x32_fp8_fp8(q.y,  wI1[0][2*kbh+1], acc[rr][0], 0, 0, 0);
                    acc[rr][0] = __builtin_amdgcn_mfma_f32_16x16x32_fp8_fp8(r2.x, wH1[0][2*kbh],   acc[rr][0], 0, 0, 0);
                    acc[rr][0] = __builtin_amdgcn_mfma_f32_16x16x32_fp8_fp8(r2.y, wH1[0][2*kbh+1], acc[rr][0], 0, 0, 0);
                    acc[rr][1] = __builtin_amdgcn_mfma_f32_16x16x32_fp8_fp8(q.x,  wI1[1][2*kbh],   acc[rr][1], 0, 0, 0);
                    acc[rr][1] = __builtin_amdgcn_mfma_f32_16x16x32_fp8_fp8(q.y,  wI1[1][2*kbh+1], acc[rr][1], 0, 0, 0);
                    acc[rr][1] = __builtin_amdgcn_mfma_f32_16x16x32_fp8_fp8(r2.x, wH1[1][2*kbh],   acc[rr][1], 0, 0, 0);
                    acc[rr][1] = __builtin_amdgcn_mfma_f32_16x16x32_fp8_fp8(r2.y, wH1[1][2*kbh+1], acc[rr][1], 0, 0, 0);
                }
            }
            #pragma unroll
            for (int rr = 0; rr < 2; ++rr)
            #pragma unroll
            for (int cc = 0; cc < 2; ++cc) {
                const int colw = g * 64 + ubk * 32 + cc * 16 + lrow;
                #pragma unroll
                for (int r = 0; r < 4; ++r)
                    gB[GIDX(rr * 16 + kgrp * 4 + r, colw)] = acc[rr][cc][r] + bw1[cc];
            }
        }
        __syncthreads();   // S4: gates1 staged

        // ===== E: nonlin1 + publish h1(p-1) =====
        if (p >= 1) {
            float4 q0 = *(float4*)&gB[GIDX(nrow, ub4)];
            float4 q1 = *(float4*)&gB[GIDX(nrow, 64 + ub4)];
            float4 q2 = *(float4*)&gB[GIDX(nrow, 128 + ub4)];
            float4 q3 = *(float4*)&gB[GIDX(nrow, 192 + ub4)];
            float hh[4];
            #pragma unroll
            for (int u = 0; u < 4; ++u) {
                float iv = (&q0.x)[u] * INV_SC, fv = (&q1.x)[u] * INV_SC;
                float gv = (&q2.x)[u] * INV_SC, ov = (&q3.x)[u] * INV_SC;
                float c = sigm(fv) * c1v[u] + sigm(iv) * tanh_f(gv);
                c1v[u] = c;
                hh[u] = sigm(ov) * tanh_f(c) * A_SC;
            }
            int pk = __builtin_amdgcn_cvt_pk_fp8_f32(hh[0], hh[1], 0, false);
            pk = __builtin_amdgcn_cvt_pk_fp8_f32(hh[2], hh[3], pk, true);
            __hip_atomic_store((uint*)(h1gg + (size_t)((p + 1) & 1) * 8192 + nrow * 256 + slc * 64 + ub4),
                               (uint)pk, __ATOMIC_RELAXED, __HIP_MEMORY_SCOPE_AGENT);
        }
        __syncthreads();   // S5: h1 publish drained
        if (p >= 1) { if (tid == 0) __hip_atomic_fetch_add(ctr1, 1u, __ATOMIC_RELAXED, __HIP_MEMORY_SCOPE_AGENT); t1 += 4; }

        // ===== F: wait + restage h0(p) (slack: layer1 + nonlin1 since arrive0) =====
        if (p < NS) {
            WAITC(ctr0, t0);
            const uint8_t* s = h0gg + (size_t)(p & 1) * 8192 + rrow * 256 + seg * 16;
            ull a0 = __hip_atomic_load((const ull*)s,       __ATOMIC_RELAXED, __HIP_MEMORY_SCOPE_AGENT);
            ull a1 = __hip_atomic_load((const ull*)(s + 8), __ATOMIC_RELAXED, __HIP_MEMORY_SCOPE_AGENT);
            *(ull*)&h0st[HADDR16(rrow, rboff0)] = a0;
            *(ull*)&h0st[HADDR16(rrow, rboff1)] = a1;
        }
        __syncthreads();   // S6: h0st ready for next phase
    }

    // ===== epilogue: restage h1(127) (parity 1), then FC head =====
    {
        WAITC(ctr1, t1);
        const uint8_t* s = h1gg + (size_t)8192 + rrow * 256 + seg * 16;
        ull a0 = __hip_atomic_load((const ull*)s,       __ATOMIC_RELAXED, __HIP_MEMORY_SCOPE_AGENT);
        ull a1 = __hip_atomic_load((const ull*)(s + 8), __ATOMIC_RELAXED, __HIP_MEMORY_SCOPE_AGENT);
        *(ull*)&h1st[HADDR16(rrow, rboff0)] = a0;
        *(ull*)&h1st[HADDR16(rrow, rboff1)] = a1;
    }
    __syncthreads();

    if (w < 2) {
        f32x4 a = {0,0,0,0};
        #pragma unroll
        for (int kbh = 0; kbh < 4; ++kbh) {
            const int gsw = ((((kgrp << 2) + kbh) ^ lrow) & 15) << 4;
            long2_t q = *(const long2_t*)&h1st[((w * 16 + lrow) << 8) + gsw];
            long b0_ = *(const long*)(WfcP + (((size_t)slc * 8 + 2 * kbh) * 64 + lane) * 8);
            long b1_ = *(const long*)(WfcP + (((size_t)slc * 8 + 2 * kbh + 1) * 64 + lane) * 8);
            a = __builtin_amdgcn_mfma_f32_16x16x32_fp8_fp8(q.x, b0_, a, 0, 0, 0);
            a = __builtin_amdgcn_mfma_f32_16x16x32_fp8_fp8(q.y, b1_, a, 0, 0, 0);
        }
        const int col = slc * 16 + lrow;
        if (col < NK) {
            float bb = bfc[col];
            #pragma unroll
            for (int r = 0; r < 4; ++r)
                out[(size_t)(rowbase + w * 16 + kgrp * 4 + r) * NK + col] = a[r] * INV_SC + bb;
        }
    }
#undef WAITC
}

// ---------------- IDM rollout (exact fp32) ----------------
__global__ void k_idm(const float* __restrict__ x, const float* __restrict__ s0,
                      const float* __restrict__ vl, float* __restrict__ out) {
    int b = blockIdx.x * 256 + threadIdx.x;
    if (b >= NB) return;
    float v = x[(size_t)b * NS * NI + (NS - 1) * NI + 0];
    float s = s0[b];
    float vlead = vl[b];
    const float den = 2.0f * sqrtf(A_MAX_ * B_SAFE_) + 1e-6f;
    float* o = out + (size_t)NB * NK + (size_t)b * NK;
    #pragma unroll 1
    for (int k = 0; k < NK; ++k) {
        float dv = vlead - v;
        float sc = fmaxf(s, 1e-6f);
        float ss = fmaxf(S0_ + v * T_HW_ + v * dv / den, 0.0f);
        float a = A_MAX_ * (1.0f - v / V_DES_ - (ss / sc) * (ss / sc));
        v = fmaxf(v + DT_ * a, 0.0f);
        s = fmaxf(s + dv * DT_, 1e-6f);
        o[k] = v;
    }
}

// ---------------- launch ----------------
extern "C" void kernel_launch(void* const* d_in, const int* in_sizes, int n_in,
                              void* d_out, int out_size, void* d_ws, size_t ws_size,
                              hipStream_t stream) {
    const float* x    = (const float*)d_in[0];
    const float* s0   = (const float*)d_in[1];
    const float* vl   = (const float*)d_in[2];
    const float* Wih0 = (const float*)d_in[3];
    const float* Whh0 = (const float*)d_in[4];
    const float* bih0 = (const float*)d_in[5];
    const float* bhh0 = (const float*)d_in[6];
    const float* Wih1 = (const float*)d_in[7];
    const float* Whh1 = (const float*)d_in[8];
    const float* bih1 = (const float*)d_in[9];
    const float* bhh1 = (const float*)d_in[10];
    const float* Wfc  = (const float*)d_in[11];
    const float* bfc  = (const float*)d_in[12];
    float* out = (float*)d_out;

    uint8_t* ws = (uint8_t*)d_ws;
    size_t off = 0;
    auto alloc = [&](size_t n) { uint8_t* p = ws + off; off += (n + 255) & ~(size_t)255; return p; };
    uint8_t* Wih0P = alloc(64 * 1 * 64 * 8);
    uint8_t* Whh0P = alloc(64 * 8 * 64 * 8);
    uint8_t* Wih1P = alloc(64 * 8 * 64 * 8);
    uint8_t* Whh1P = alloc(64 * 8 * 64 * 8);
    uint8_t* WfcP  = alloc(4 * 8 * 64 * 8);
    float* b0 = (float*)alloc(NG * 4);
    float* b1 = (float*)alloc(NG * 4);
    uint8_t* x8 = alloc((size_t)NB * NS * NI);
    // h exchange zone (memset each launch): h0g | h1g | ctrs, contiguous
    uint8_t* h0g = alloc((size_t)64 * 16384);
    uint8_t* h1g = alloc((size_t)64 * 16384);
    uint*    ctrs = (uint*)alloc(64 * 32 * 4);
    size_t hz = (size_t)(((uint8_t*)ctrs + 64 * 32 * 4) - h0g);

    k_pack<<<(64 * 1 * 64 + 255) / 256, 256, 0, stream>>>(Wih0, Wih0P, 64, 1, NG, NI);
    k_pack<<<(64 * 8 * 64 + 255) / 256, 256, 0, stream>>>(Whh0, Whh0P, 64, 8, NG, NH);
    k_pack<<<(64 * 8 * 64 + 255) / 256, 256, 0, stream>>>(Wih1, Wih1P, 64, 8, NG, NH);
    k_pack<<<(64 * 8 * 64 + 255) / 256, 256, 0, stream>>>(Whh1, Whh1P, 64, 8, NG, NH);
    k_pack<<<(4 * 8 * 64 + 255) / 256, 256, 0, stream>>>(Wfc, WfcP, 4, 8, NK, NH);
    k_bias<<<(2 * NG + 255) / 256, 256, 0, stream>>>(bih0, bhh0, bih1, bhh1, b0, b1);
    k_x8<<<(NB * NS * NI + 255) / 256, 256, 0, stream>>>(x, x8);
    hipMemsetAsync(h0g, 0, hz, stream);

    void* kargs[] = { (void*)&x8, (void*)&Wih0P, (void*)&Whh0P, (void*)&Wih1P, (void*)&Whh1P,
                      (void*)&WfcP, (void*)&b0, (void*)&b1, (void*)&bfc,
                      (void*)&h0g, (void*)&h1g, (void*)&ctrs, (void*)&out };
    hipError_t ce = hipLaunchCooperativeKernel((const void*)k_lstm8, dim3(256), dim3(512), kargs, 0, stream);
    if (ce != hipSuccess) {
        k_lstm8<<<256, 512, 0, stream>>>(x8, Wih0P, Whh0P, Wih1P, Whh1P, WfcP, b0, b1, bfc, h0g, h1g, ctrs, out);
    }
    k_idm<<<(NB + 255) / 256, 256, 0, stream>>>(x, s0, vl, out);
}